// Round 6
// baseline (845.569 us; speedup 1.0000x reference)
//
#include <hip/hip_runtime.h>
#include <hip/hip_fp16.h>

// Problem constants (from reference)
#define Nn 200000
#define Ee 6400000
#define EP 6600000            // Ee + Nn self loops
#define Hh 9
#define Ll 4
#define Gg 2000
#define Cc 2
#define JK 36                 // Ll * Hh
#define NBK ((Nn + 255) >> 8) // 782 fine buckets (256 nodes)
#define NCB ((Nn + 4095) >> 12) // 49 coarse buckets (4096 nodes)
#define EPB 8192              // edges per phase-A block
#define NBLKA ((EP + EPB - 1) / EPB) // 806
#define NB ((Nn + 255) / 256) // 782
#define NPB 64                // nodes per k_node_agg block (quad per node)
#define NAB (Nn / NPB)        // 3125 blocks
#define CAP 4096              // staged csr entries per block (16 KB)

union H2F { __half2 h; float f; };

// ============ CSR build: coarse-first radix, zero hot global atomics ============

// Global fine-bucket histogram (782 bins) via per-block LDS hist.
__global__ __launch_bounds__(256) void k_count(
    const int* __restrict__ dst, int* __restrict__ fine_tot)
{
    __shared__ int lf[NBK];
    for (int k = threadIdx.x; k < NBK; k += 256) lf[k] = 0;
    __syncthreads();
    int base = blockIdx.x * EPB;
    for (int j = 0; j < EPB; j += 256) {
        int e = base + j + threadIdx.x;
        if (e < EP) {
            int d = (e < Ee) ? dst[e] : (e - Ee);
            atomicAdd(&lf[d >> 8], 1);
        }
    }
    __syncthreads();
    for (int k = threadIdx.x; k < NBK; k += 256)
        if (lf[k]) atomicAdd(&fine_tot[k], lf[k]);
}

// Scan fine totals -> fine_base; derive coarse base + cursors.
__global__ __launch_bounds__(1024) void k_scan(
    const int* __restrict__ fine_tot, int* __restrict__ fine_base,
    int* __restrict__ cbase, int* __restrict__ ccur, int* __restrict__ row_ptr)
{
    __shared__ int s[1024];
    int t = threadIdx.x;
    int v = (t < NBK) ? fine_tot[t] : 0;
    s[t] = v; __syncthreads();
    for (int off = 1; off < 1024; off <<= 1) {
        int u = (t >= off) ? s[t - off] : 0;
        __syncthreads();
        s[t] += u;
        __syncthreads();
    }
    if (t < NBK) fine_base[t] = s[t] - v;
    if (t == 0) { fine_base[NBK] = EP; row_ptr[Nn] = EP; }
    __syncthreads();
    // coarse base = fine_base at multiples of 16
    if (t < NCB) {
        int cb = fine_base[t << 4];
        cbase[t] = cb;
        ccur[t]  = cb;
    }
    if (t == 0) cbase[NCB] = EP;
}

// Phase A: scatter edges into 49 coarse buckets. Long runs (~167 entries)
// -> write amp ~1.1; start offsets via ONE global atomicAdd per bucket.
// Payload: src (18b) | dst low 12 bits << 18.
__global__ __launch_bounds__(256) void kA_scatter(
    const int* __restrict__ src, const int* __restrict__ dst,
    int* __restrict__ ccur, unsigned* __restrict__ bucketed)
{
    __shared__ int lh[NCB];
    __shared__ int cur[NCB];
    int t = threadIdx.x;
    if (t < NCB) lh[t] = 0;
    __syncthreads();
    int base = blockIdx.x * EPB;
    for (int j = 0; j < EPB; j += 256) {
        int e = base + j + t;
        if (e < EP) {
            int d = (e < Ee) ? dst[e] : (e - Ee);
            atomicAdd(&lh[d >> 12], 1);
        }
    }
    __syncthreads();
    if (t < NCB) cur[t] = atomicAdd(&ccur[t], lh[t]);   // block's run start
    __syncthreads();
    for (int j = 0; j < EPB; j += 256) {
        int e = base + j + t;
        if (e < EP) {
            int s, d;
            if (e < Ee) { s = src[e]; d = dst[e]; } else { s = e - Ee; d = s; }
            int pos = atomicAdd(&cur[d >> 12], 1);
            bucketed[pos] = (unsigned)s | ((unsigned)(d & 4095) << 18);
        }
    }
}

// Phase B: one block per fine bucket; scans parent coarse region (L2-shared
// with 15 siblings), filters own entries, 256-bin LDS counting sort, scatters
// into its private ~33KB csr window. Emits row_ptr.
__global__ __launch_bounds__(256) void kB_csr(
    const unsigned* __restrict__ bucketed, const int* __restrict__ cbase,
    const int* __restrict__ fine_base, int* __restrict__ row_ptr,
    int* __restrict__ csr_src)
{
    __shared__ int bh[256];
    __shared__ int cur[256];
    int k = blockIdx.x;
    unsigned f = (unsigned)(k & 15);
    int beg = cbase[k >> 4], end = cbase[(k >> 4) + 1];
    int t = threadIdx.x;
    bh[t] = 0;
    __syncthreads();
    for (int i = beg + t; i < end; i += 256) {
        unsigned p = bucketed[i];
        if ((p >> 26) == f) atomicAdd(&bh[(p >> 18) & 255], 1);
    }
    __syncthreads();
    int v = bh[t];
    for (int off = 1; off < 256; off <<= 1) {
        int u = (t >= off) ? bh[t - off] : 0;
        __syncthreads();
        bh[t] += u;
        __syncthreads();
    }
    int pos0 = fine_base[k] + bh[t] - v;   // exclusive scan
    int node = (k << 8) + t;
    if (node < Nn) row_ptr[node] = pos0;
    cur[t] = pos0;
    __syncthreads();
    for (int i = beg + t; i < end; i += 256) {
        unsigned p = bucketed[i];
        if ((p >> 26) == f) {
            int pos = atomicAdd(&cur[(p >> 18) & 255], 1);
            csr_src[pos] = (int)(p & 0x3FFFFu);
        }
    }
}

// ============ per-layer kernels ============

// h line layout per node: 32 B = 8 floats.
//   floats[0..3] = h0..h7 as 4x half2, float[4] low half = h8,
//   float[5] = alpha_s (fp32), float[6] = alpha_d (fp32), float[7] pad.
// fp16 features halve gather bytes (6.4 MB table, mostly L2-resident);
// logits stay fp32 so softmax weights are exact.
__global__ __launch_bounds__(256) void k_transform(
    const float* __restrict__ xin, int xstride,
    const float* __restrict__ Wl,
    const float* __restrict__ asrc, const float* __restrict__ adst,
    float* __restrict__ h)
{
    int i = blockIdx.x * blockDim.x + threadIdx.x;
    if (i >= Nn) return;
    const float* xp = xin + (size_t)i * xstride;
    float xi[Hh];
#pragma unroll
    for (int k = 0; k < Hh; ++k) xi[k] = xp[k];
    float hv[Hh];
#pragma unroll
    for (int j = 0; j < Hh; ++j) {
        float s = 0.f;
#pragma unroll
        for (int k = 0; k < Hh; ++k) s += xi[k] * Wl[k * Hh + j];
        hv[j] = s;
    }
    float as = 0.f, ad = 0.f;
#pragma unroll
    for (int j = 0; j < Hh; ++j) { as += hv[j] * asrc[j]; ad += hv[j] * adst[j]; }
    H2F u01, u23, u45, u67, u8p;
    u01.h = __floats2half2_rn(hv[0], hv[1]);
    u23.h = __floats2half2_rn(hv[2], hv[3]);
    u45.h = __floats2half2_rn(hv[4], hv[5]);
    u67.h = __floats2half2_rn(hv[6], hv[7]);
    u8p.h = __floats2half2_rn(hv[8], 0.f);
    float4* hp = (float4*)(h + ((size_t)i << 3));
    hp[0] = make_float4(u01.f, u23.f, u45.f, u67.f);
    hp[1] = make_float4(u8p.f, as, ad, 0.f);
}

// Quad-per-node gather with LDS-staged CSR.
// Single-pass softmax: |logits| << 88 so exp never overflows; ratio exact.
__global__ __launch_bounds__(256) void k_node_agg(
    const int* __restrict__ rp, const int* __restrict__ csr,
    const float* __restrict__ h, const float* __restrict__ biasl,
    float* __restrict__ jk, int l)
{
    __shared__ int scsr[CAP];
    __shared__ int srp[NPB + 1];
    const int nbase = blockIdx.x * NPB;
    const int t = threadIdx.x;
    if (t <= NPB) srp[t] = rp[nbase + t];   // nbase+NPB <= Nn; rp[Nn] = EP
    __syncthreads();
    const int beg_blk = srp[0];
    const int nseg = srp[NPB] - beg_blk;
    const bool use_lds = (nseg <= CAP);
    if (use_lds)
        for (int j = t; j < nseg; j += 256) scsr[j] = csr[beg_blk + j];
    __syncthreads();

    const int ni = t >> 2;          // node within block
    const int q  = t & 3;           // lane within quad
    const int i  = nbase + ni;
    const float c = h[((size_t)i << 3) + 6];   // own alpha_d (fp32)
    float a0=0,a1=0,a2=0,a3=0,a4=0,a5=0,a6=0,a7=0,a8=0,den=0;
    if (use_lds) {
        int idx = srp[ni] - beg_blk + q;
        const int iend = srp[ni + 1] - beg_blk;
        int s = (idx < iend) ? scsr[idx] : 0;
        while (idx < iend) {
            int nidx = idx + 4;
            int sn = (nidx < iend) ? scsr[nidx] : 0;   // prefetch next src
            const float4* hp = (const float4*)(h + ((size_t)s << 3));
            float4 F0 = hp[0], F1 = hp[1];
            float lg = F1.y + c;
            lg = lg > 0.f ? lg : 0.2f * lg;            // leaky_relu(0.2)
            float w = __expf(lg);
            H2F u; float2 p;
            u.f = F0.x; p = __half22float2(u.h); a0 += w*p.x; a1 += w*p.y;
            u.f = F0.y; p = __half22float2(u.h); a2 += w*p.x; a3 += w*p.y;
            u.f = F0.z; p = __half22float2(u.h); a4 += w*p.x; a5 += w*p.y;
            u.f = F0.w; p = __half22float2(u.h); a6 += w*p.x; a7 += w*p.y;
            u.f = F1.x; p = __half22float2(u.h); a8 += w*p.x;
            den += w;
            idx = nidx; s = sn;
        }
    } else {
        for (int e = srp[ni] + q; e < srp[ni + 1]; e += 4) {
            int s = csr[e];
            const float4* hp = (const float4*)(h + ((size_t)s << 3));
            float4 F0 = hp[0], F1 = hp[1];
            float lg = F1.y + c;
            lg = lg > 0.f ? lg : 0.2f * lg;
            float w = __expf(lg);
            H2F u; float2 p;
            u.f = F0.x; p = __half22float2(u.h); a0 += w*p.x; a1 += w*p.y;
            u.f = F0.y; p = __half22float2(u.h); a2 += w*p.x; a3 += w*p.y;
            u.f = F0.z; p = __half22float2(u.h); a4 += w*p.x; a5 += w*p.y;
            u.f = F0.w; p = __half22float2(u.h); a6 += w*p.x; a7 += w*p.y;
            u.f = F1.x; p = __half22float2(u.h); a8 += w*p.x;
            den += w;
        }
    }
#pragma unroll
    for (int m = 1; m <= 2; m <<= 1) {
        a0 += __shfl_xor(a0, m); a1 += __shfl_xor(a1, m);
        a2 += __shfl_xor(a2, m); a3 += __shfl_xor(a3, m);
        a4 += __shfl_xor(a4, m); a5 += __shfl_xor(a5, m);
        a6 += __shfl_xor(a6, m); a7 += __shfl_xor(a7, m);
        a8 += __shfl_xor(a8, m); den += __shfl_xor(den, m);
    }
    if (q == 0) {
        float inv = 1.f / den;          // den >= 1 (self-loop term)
        float* jp = jk + (size_t)i * JK + l * Hh;
        float o;
        o = a0*inv + biasl[0]; jp[0] = fmaxf(o, 0.f);
        o = a1*inv + biasl[1]; jp[1] = fmaxf(o, 0.f);
        o = a2*inv + biasl[2]; jp[2] = fmaxf(o, 0.f);
        o = a3*inv + biasl[3]; jp[3] = fmaxf(o, 0.f);
        o = a4*inv + biasl[4]; jp[4] = fmaxf(o, 0.f);
        o = a5*inv + biasl[5]; jp[5] = fmaxf(o, 0.f);
        o = a6*inv + biasl[6]; jp[6] = fmaxf(o, 0.f);
        o = a7*inv + biasl[7]; jp[7] = fmaxf(o, 0.f);
        o = a8*inv + biasl[8]; jp[8] = fmaxf(o, 0.f);
    }
}

// ============ pool + fc ============

// batch is sorted -> graphs are contiguous node ranges. Build range starts.
__global__ __launch_bounds__(256) void k_graph_ptr(
    const int* __restrict__ batch, int* __restrict__ gp)
{
    int i = blockIdx.x * 256 + threadIdx.x;
    if (i >= Nn) return;
    int b = batch[i];
    if (i == 0) {
        for (int g = 0; g <= b; ++g) gp[g] = 0;
    } else {
        int pb = batch[i - 1];
        for (int g = pb + 1; g <= b; ++g) gp[g] = i;
    }
    if (i == Nn - 1) {
        for (int g = b + 1; g <= Gg; ++g) gp[g] = Nn;
    }
}

// Segmented max, one thread per (graph, col). Post-relu values >= 0 and
// init 0 reproduces the isfinite->0 guard for empty graphs.
__global__ __launch_bounds__(256) void k_pool_seg(
    const float* __restrict__ jk, const int* __restrict__ gp,
    float* __restrict__ pooled)
{
    int t = blockIdx.x * 256 + threadIdx.x;
    if (t >= Gg * JK) return;
    int g = t / JK, col = t - g * JK;
    int beg = gp[g], end = gp[g + 1];
    float m = 0.f;
    for (int i = beg; i < end; ++i)
        m = fmaxf(m, jk[(size_t)i * JK + col]);
    pooled[t] = m;
}

__global__ __launch_bounds__(256) void k_fc(
    const float* __restrict__ pooled, const float* __restrict__ fcw,
    const float* __restrict__ fcb, float* __restrict__ out)
{
    int t = blockIdx.x * blockDim.x + threadIdx.x;
    if (t >= Gg * Cc) return;
    int g = t / Cc, c = t - g * Cc;
    float s = fcb[c];
    const float* pp = pooled + (size_t)g * JK;
#pragma unroll
    for (int j = 0; j < JK; ++j) s += pp[j] * fcw[j * Cc + c];
    out[t] = s;
}

extern "C" void kernel_launch(void* const* d_in, const int* in_sizes, int n_in,
                              void* d_out, int out_size, void* d_ws, size_t ws_size,
                              hipStream_t stream) {
    const float* x      = (const float*)d_in[0];   // [N,9]
    const int*   ei     = (const int*)d_in[1];     // [2,E]: src row then dst row
    const int*   batch  = (const int*)d_in[2];     // [N] sorted
    const float* W      = (const float*)d_in[3];   // [L,9,9]
    const float* a_src  = (const float*)d_in[4];   // [L,9]
    const float* a_dst  = (const float*)d_in[5];   // [L,9]
    const float* bias   = (const float*)d_in[6];   // [L,9]
    const float* fc_w   = (const float*)d_in[7];   // [36,2]
    const float* fc_b   = (const float*)d_in[8];   // [2]
    float* out = (float*)d_out;

    // Workspace layout (~63 MB live). bucketed aliases jk (dead before jk
    // is first written — same-stream ordering).
    float* ws        = (float*)d_ws;
    float* h         = ws;                                // Nn*8 floats (6.4MB)
    float* jk        = h + (size_t)Nn * 8;                // Nn*JK (28.8MB)
    float* pooled    = jk + (size_t)Nn * JK;              // Gg*JK
    int* row_ptr     = (int*)(pooled + (size_t)Gg * JK);  // Nn+1
    int* gp          = row_ptr + Nn + 1;                  // Gg+1
    int* fine_tot    = gp + Gg + 1;                       // NBK
    int* fine_base   = fine_tot + NBK;                    // NBK+1
    int* cbase       = fine_base + NBK + 1;               // NCB+1
    int* ccur        = cbase + NCB + 1;                   // NCB
    int* csr_src     = ccur + NCB;                        // EP (26.4MB)
    unsigned* bucketed = (unsigned*)jk;                   // EP alias (26.4MB)

    const int* srcp = ei;
    const int* dstp = ei + Ee;

    // CSR build (edge structure is layer-invariant)
    hipMemsetAsync(fine_tot, 0, NBK * sizeof(int), stream);
    k_count   <<<NBLKA, 256, 0, stream>>>(dstp, fine_tot);
    k_scan    <<<1, 1024, 0, stream>>>(fine_tot, fine_base, cbase, ccur, row_ptr);
    kA_scatter<<<NBLKA, 256, 0, stream>>>(srcp, dstp, ccur, bucketed);
    kB_csr    <<<NBK, 256, 0, stream>>>(bucketed, cbase, fine_base, row_ptr, csr_src);

    for (int l = 0; l < Ll; ++l) {
        const float* xin = (l == 0) ? x : (jk + (size_t)(l - 1) * Hh);
        int xstride      = (l == 0) ? Hh : JK;
        k_transform<<<NB, 256, 0, stream>>>(xin, xstride, W + l * Hh * Hh,
                                            a_src + l * Hh, a_dst + l * Hh, h);
        k_node_agg<<<NAB, 256, 0, stream>>>(row_ptr, csr_src,
                                            h, bias + l * Hh, jk, l);
    }
    k_graph_ptr<<<NB, 256, 0, stream>>>(batch, gp);
    k_pool_seg<<<(Gg * JK + 255) / 256, 256, 0, stream>>>(jk, gp, pooled);
    k_fc<<<(Gg * Cc + 255) / 256, 256, 0, stream>>>(pooled, fc_w, fc_b, out);
}

// Round 7
// 586.495 us; speedup vs baseline: 1.4417x; 1.4417x over previous
//
#include <hip/hip_runtime.h>
#include <hip/hip_fp16.h>

// Problem constants (from reference)
#define Nn 200000
#define Ee 6400000
#define EP 6600000            // Ee + Nn self loops
#define Hh 9
#define Ll 4
#define Gg 2000
#define Cc 2
#define JK 36                 // Ll * Hh
#define NCB ((Nn + 1023) >> 10) // 196 coarse buckets (1024 nodes each)
#define EPB 8192              // edges per phase-A block
#define NBLKA ((EP + EPB - 1) / EPB) // 806
#define NB ((Nn + 255) / 256) // 782
#define NPB 64                // nodes per k_node_agg block (quad per node)
#define NAB (Nn / NPB)        // 3125 blocks
#define CAP 4096              // staged csr entries per block (16 KB)

union H2F { __half2 h; float f; };

// ========= CSR build: coarse radix (196 buckets) + per-bucket LDS sort =========

// Global coarse histogram (196 bins) via per-block LDS hist.
__global__ __launch_bounds__(256) void k_count(
    const int* __restrict__ dst, int* __restrict__ ctot)
{
    __shared__ int lh[NCB];
    int t = threadIdx.x;
    if (t < NCB) lh[t] = 0;
    __syncthreads();
    int base = blockIdx.x * EPB;
    for (int j = 0; j < EPB; j += 256) {
        int e = base + j + t;
        if (e < EP) {
            int d = (e < Ee) ? dst[e] : (e - Ee);
            atomicAdd(&lh[d >> 10], 1);
        }
    }
    __syncthreads();
    if (t < NCB && lh[t]) atomicAdd(&ctot[t], lh[t]);
}

// Scan coarse totals -> cbase, ccur.
__global__ __launch_bounds__(256) void k_scan(
    const int* __restrict__ ctot, int* __restrict__ cbase,
    int* __restrict__ ccur, int* __restrict__ row_ptr)
{
    __shared__ int s[256];
    int t = threadIdx.x;
    int v = (t < NCB) ? ctot[t] : 0;
    s[t] = v; __syncthreads();
    for (int off = 1; off < 256; off <<= 1) {
        int u = (t >= off) ? s[t - off] : 0;
        __syncthreads();
        s[t] += u;
        __syncthreads();
    }
    if (t < NCB) { cbase[t] = s[t] - v; ccur[t] = s[t] - v; }
    if (t == 0) { cbase[NCB] = EP; row_ptr[Nn] = EP; }
}

// Phase A: scatter edges into 196 coarse buckets. Runs ~42 entries (168B)
// -> write amp ~1.4; block start offsets via ONE global atomicAdd per bucket.
// Payload: src (18b) | dst low 10 bits << 18.
__global__ __launch_bounds__(256) void kA_scatter(
    const int* __restrict__ src, const int* __restrict__ dst,
    int* __restrict__ ccur, unsigned* __restrict__ bucketed)
{
    __shared__ int lh[NCB];
    __shared__ int cur[NCB];
    int t = threadIdx.x;
    if (t < NCB) lh[t] = 0;
    __syncthreads();
    int base = blockIdx.x * EPB;
    for (int j = 0; j < EPB; j += 256) {
        int e = base + j + t;
        if (e < EP) {
            int d = (e < Ee) ? dst[e] : (e - Ee);
            atomicAdd(&lh[d >> 10], 1);
        }
    }
    __syncthreads();
    if (t < NCB) cur[t] = atomicAdd(&ccur[t], lh[t]);   // block's run start
    __syncthreads();
    for (int j = 0; j < EPB; j += 256) {
        int e = base + j + t;
        if (e < EP) {
            int s, d;
            if (e < Ee) { s = src[e]; d = dst[e]; } else { s = e - Ee; d = s; }
            int pos = atomicAdd(&cur[d >> 10], 1);
            bucketed[pos] = (unsigned)s | ((unsigned)(d & 1023) << 18);
        }
    }
}

// Phase B: ONE 1024-thread block per coarse bucket; 1024-bin LDS counting
// sort. Region read exactly twice, csr written once. row_ptr analytic.
__global__ __launch_bounds__(1024) void kB_csr(
    const unsigned* __restrict__ bucketed, const int* __restrict__ cbase,
    int* __restrict__ row_ptr, int* __restrict__ csr_src)
{
    __shared__ int bh[1024];
    __shared__ int cur[1024];
    int k = blockIdx.x;
    int beg = cbase[k], end = cbase[k + 1];
    int t = threadIdx.x;
    bh[t] = 0;
    __syncthreads();
    for (int i = beg + t; i < end; i += 1024)
        atomicAdd(&bh[(bucketed[i] >> 18) & 1023], 1);
    __syncthreads();
    int v = bh[t];
    for (int off = 1; off < 1024; off <<= 1) {
        int u = (t >= off) ? bh[t - off] : 0;
        __syncthreads();
        bh[t] += u;
        __syncthreads();
    }
    int pos0 = beg + bh[t] - v;       // exclusive scan
    int node = (k << 10) + t;
    if (node < Nn) row_ptr[node] = pos0;
    cur[t] = pos0;
    __syncthreads();
    for (int i = beg + t; i < end; i += 1024) {
        unsigned p = bucketed[i];
        int pos = atomicAdd(&cur[(p >> 18) & 1023], 1);
        csr_src[pos] = (int)(p & 0x3FFFFu);
    }
}

// ============ per-layer kernels ============

// h line layout per node: 32 B = 8 floats.
//   floats[0..3] = h0..h7 as 4x half2, float[4] low half = h8,
//   float[5] = alpha_s (fp32), float[6] = alpha_d (fp32), float[7] pad.
__global__ __launch_bounds__(256) void k_transform(
    const float* __restrict__ xin, int xstride,
    const float* __restrict__ Wl,
    const float* __restrict__ asrc, const float* __restrict__ adst,
    float* __restrict__ h)
{
    int i = blockIdx.x * blockDim.x + threadIdx.x;
    if (i >= Nn) return;
    const float* xp = xin + (size_t)i * xstride;
    float xi[Hh];
#pragma unroll
    for (int k = 0; k < Hh; ++k) xi[k] = xp[k];
    float hv[Hh];
#pragma unroll
    for (int j = 0; j < Hh; ++j) {
        float s = 0.f;
#pragma unroll
        for (int k = 0; k < Hh; ++k) s += xi[k] * Wl[k * Hh + j];
        hv[j] = s;
    }
    float as = 0.f, ad = 0.f;
#pragma unroll
    for (int j = 0; j < Hh; ++j) { as += hv[j] * asrc[j]; ad += hv[j] * adst[j]; }
    H2F u01, u23, u45, u67, u8p;
    u01.h = __floats2half2_rn(hv[0], hv[1]);
    u23.h = __floats2half2_rn(hv[2], hv[3]);
    u45.h = __floats2half2_rn(hv[4], hv[5]);
    u67.h = __floats2half2_rn(hv[6], hv[7]);
    u8p.h = __floats2half2_rn(hv[8], 0.f);
    float4* hp = (float4*)(h + ((size_t)i << 3));
    hp[0] = make_float4(u01.f, u23.f, u45.f, u67.f);
    hp[1] = make_float4(u8p.f, as, ad, 0.f);
}

// Quad-per-node gather with LDS-staged CSR.
// Single-pass softmax: |logits| << 88 so exp never overflows; ratio exact.
__global__ __launch_bounds__(256) void k_node_agg(
    const int* __restrict__ rp, const int* __restrict__ csr,
    const float* __restrict__ h, const float* __restrict__ biasl,
    float* __restrict__ jk, int l)
{
    __shared__ int scsr[CAP];
    __shared__ int srp[NPB + 1];
    const int nbase = blockIdx.x * NPB;
    const int t = threadIdx.x;
    if (t <= NPB) srp[t] = rp[nbase + t];   // nbase+NPB <= Nn; rp[Nn] = EP
    __syncthreads();
    const int beg_blk = srp[0];
    const int nseg = srp[NPB] - beg_blk;
    const bool use_lds = (nseg <= CAP);
    if (use_lds)
        for (int j = t; j < nseg; j += 256) scsr[j] = csr[beg_blk + j];
    __syncthreads();

    const int ni = t >> 2;          // node within block
    const int q  = t & 3;           // lane within quad
    const int i  = nbase + ni;
    const float c = h[((size_t)i << 3) + 6];   // own alpha_d (fp32)
    float a0=0,a1=0,a2=0,a3=0,a4=0,a5=0,a6=0,a7=0,a8=0,den=0;
    if (use_lds) {
        int idx = srp[ni] - beg_blk + q;
        const int iend = srp[ni + 1] - beg_blk;
        int s = (idx < iend) ? scsr[idx] : 0;
        while (idx < iend) {
            int nidx = idx + 4;
            int sn = (nidx < iend) ? scsr[nidx] : 0;   // prefetch next src
            const float4* hp = (const float4*)(h + ((size_t)s << 3));
            float4 F0 = hp[0], F1 = hp[1];
            float lg = F1.y + c;
            lg = lg > 0.f ? lg : 0.2f * lg;            // leaky_relu(0.2)
            float w = __expf(lg);
            H2F u; float2 p;
            u.f = F0.x; p = __half22float2(u.h); a0 += w*p.x; a1 += w*p.y;
            u.f = F0.y; p = __half22float2(u.h); a2 += w*p.x; a3 += w*p.y;
            u.f = F0.z; p = __half22float2(u.h); a4 += w*p.x; a5 += w*p.y;
            u.f = F0.w; p = __half22float2(u.h); a6 += w*p.x; a7 += w*p.y;
            u.f = F1.x; p = __half22float2(u.h); a8 += w*p.x;
            den += w;
            idx = nidx; s = sn;
        }
    } else {
        for (int e = srp[ni] + q; e < srp[ni + 1]; e += 4) {
            int s = csr[e];
            const float4* hp = (const float4*)(h + ((size_t)s << 3));
            float4 F0 = hp[0], F1 = hp[1];
            float lg = F1.y + c;
            lg = lg > 0.f ? lg : 0.2f * lg;
            float w = __expf(lg);
            H2F u; float2 p;
            u.f = F0.x; p = __half22float2(u.h); a0 += w*p.x; a1 += w*p.y;
            u.f = F0.y; p = __half22float2(u.h); a2 += w*p.x; a3 += w*p.y;
            u.f = F0.z; p = __half22float2(u.h); a4 += w*p.x; a5 += w*p.y;
            u.f = F0.w; p = __half22float2(u.h); a6 += w*p.x; a7 += w*p.y;
            u.f = F1.x; p = __half22float2(u.h); a8 += w*p.x;
            den += w;
        }
    }
#pragma unroll
    for (int m = 1; m <= 2; m <<= 1) {
        a0 += __shfl_xor(a0, m); a1 += __shfl_xor(a1, m);
        a2 += __shfl_xor(a2, m); a3 += __shfl_xor(a3, m);
        a4 += __shfl_xor(a4, m); a5 += __shfl_xor(a5, m);
        a6 += __shfl_xor(a6, m); a7 += __shfl_xor(a7, m);
        a8 += __shfl_xor(a8, m); den += __shfl_xor(den, m);
    }
    if (q == 0) {
        float inv = 1.f / den;          // den >= 1 (self-loop term)
        float* jp = jk + (size_t)i * JK + l * Hh;
        float o;
        o = a0*inv + biasl[0]; jp[0] = fmaxf(o, 0.f);
        o = a1*inv + biasl[1]; jp[1] = fmaxf(o, 0.f);
        o = a2*inv + biasl[2]; jp[2] = fmaxf(o, 0.f);
        o = a3*inv + biasl[3]; jp[3] = fmaxf(o, 0.f);
        o = a4*inv + biasl[4]; jp[4] = fmaxf(o, 0.f);
        o = a5*inv + biasl[5]; jp[5] = fmaxf(o, 0.f);
        o = a6*inv + biasl[6]; jp[6] = fmaxf(o, 0.f);
        o = a7*inv + biasl[7]; jp[7] = fmaxf(o, 0.f);
        o = a8*inv + biasl[8]; jp[8] = fmaxf(o, 0.f);
    }
}

// ============ pool + fc ============

// batch is sorted -> graphs are contiguous node ranges. Build range starts.
__global__ __launch_bounds__(256) void k_graph_ptr(
    const int* __restrict__ batch, int* __restrict__ gp)
{
    int i = blockIdx.x * 256 + threadIdx.x;
    if (i >= Nn) return;
    int b = batch[i];
    if (i == 0) {
        for (int g = 0; g <= b; ++g) gp[g] = 0;
    } else {
        int pb = batch[i - 1];
        for (int g = pb + 1; g <= b; ++g) gp[g] = i;
    }
    if (i == Nn - 1) {
        for (int g = b + 1; g <= Gg; ++g) gp[g] = Nn;
    }
}

// Segmented max, one thread per (graph, col). Post-relu values >= 0 and
// init 0 reproduces the isfinite->0 guard for empty graphs.
__global__ __launch_bounds__(256) void k_pool_seg(
    const float* __restrict__ jk, const int* __restrict__ gp,
    float* __restrict__ pooled)
{
    int t = blockIdx.x * 256 + threadIdx.x;
    if (t >= Gg * JK) return;
    int g = t / JK, col = t - g * JK;
    int beg = gp[g], end = gp[g + 1];
    float m = 0.f;
    for (int i = beg; i < end; ++i)
        m = fmaxf(m, jk[(size_t)i * JK + col]);
    pooled[t] = m;
}

__global__ __launch_bounds__(256) void k_fc(
    const float* __restrict__ pooled, const float* __restrict__ fcw,
    const float* __restrict__ fcb, float* __restrict__ out)
{
    int t = blockIdx.x * blockDim.x + threadIdx.x;
    if (t >= Gg * Cc) return;
    int g = t / Cc, c = t - g * Cc;
    float s = fcb[c];
    const float* pp = pooled + (size_t)g * JK;
#pragma unroll
    for (int j = 0; j < JK; ++j) s += pp[j] * fcw[j * Cc + c];
    out[t] = s;
}

extern "C" void kernel_launch(void* const* d_in, const int* in_sizes, int n_in,
                              void* d_out, int out_size, void* d_ws, size_t ws_size,
                              hipStream_t stream) {
    const float* x      = (const float*)d_in[0];   // [N,9]
    const int*   ei     = (const int*)d_in[1];     // [2,E]: src row then dst row
    const int*   batch  = (const int*)d_in[2];     // [N] sorted
    const float* W      = (const float*)d_in[3];   // [L,9,9]
    const float* a_src  = (const float*)d_in[4];   // [L,9]
    const float* a_dst  = (const float*)d_in[5];   // [L,9]
    const float* bias   = (const float*)d_in[6];   // [L,9]
    const float* fc_w   = (const float*)d_in[7];   // [36,2]
    const float* fc_b   = (const float*)d_in[8];   // [2]
    float* out = (float*)d_out;

    // Workspace layout (~63 MB live). bucketed aliases jk (dead before jk
    // is first written — same-stream ordering).
    float* ws        = (float*)d_ws;
    float* h         = ws;                                // Nn*8 floats (6.4MB)
    float* jk        = h + (size_t)Nn * 8;                // Nn*JK (28.8MB)
    float* pooled    = jk + (size_t)Nn * JK;              // Gg*JK
    int* row_ptr     = (int*)(pooled + (size_t)Gg * JK);  // Nn+1
    int* gp          = row_ptr + Nn + 1;                  // Gg+1
    int* ctot        = gp + Gg + 1;                       // NCB
    int* cbase       = ctot + NCB;                        // NCB+1
    int* ccur        = cbase + NCB + 1;                   // NCB
    int* csr_src     = ccur + NCB;                        // EP (26.4MB)
    unsigned* bucketed = (unsigned*)jk;                   // EP alias (26.4MB)

    const int* srcp = ei;
    const int* dstp = ei + Ee;

    // CSR build (edge structure is layer-invariant)
    hipMemsetAsync(ctot, 0, NCB * sizeof(int), stream);
    k_count   <<<NBLKA, 256, 0, stream>>>(dstp, ctot);
    k_scan    <<<1, 256, 0, stream>>>(ctot, cbase, ccur, row_ptr);
    kA_scatter<<<NBLKA, 256, 0, stream>>>(srcp, dstp, ccur, bucketed);
    kB_csr    <<<NCB, 1024, 0, stream>>>(bucketed, cbase, row_ptr, csr_src);

    for (int l = 0; l < Ll; ++l) {
        const float* xin = (l == 0) ? x : (jk + (size_t)(l - 1) * Hh);
        int xstride      = (l == 0) ? Hh : JK;
        k_transform<<<NB, 256, 0, stream>>>(xin, xstride, W + l * Hh * Hh,
                                            a_src + l * Hh, a_dst + l * Hh, h);
        k_node_agg<<<NAB, 256, 0, stream>>>(row_ptr, csr_src,
                                            h, bias + l * Hh, jk, l);
    }
    k_graph_ptr<<<NB, 256, 0, stream>>>(batch, gp);
    k_pool_seg<<<(Gg * JK + 255) / 256, 256, 0, stream>>>(jk, gp, pooled);
    k_fc<<<(Gg * Cc + 255) / 256, 256, 0, stream>>>(pooled, fc_w, fc_b, out);
}

// Round 8
// 554.085 us; speedup vs baseline: 1.5261x; 1.0585x over previous
//
#include <hip/hip_runtime.h>
#include <hip/hip_fp16.h>

// Problem constants (from reference)
#define Nn 200000
#define Ee 6400000
#define EP 6600000            // Ee + Nn self loops
#define Hh 9
#define Ll 4
#define Gg 2000
#define Cc 2
#define JK 36                 // Ll * Hh
#define NCB ((Nn + 1023) >> 10) // 196 coarse buckets (1024 nodes each)
#define EPB 8192              // edges per phase-A block
#define NBLKA ((EP + EPB - 1) / EPB) // 806
#define NB ((Nn + 255) / 256) // 782
#define NPB 32                // nodes per k_node_agg block (oct per node)
#define NAB (Nn / NPB)        // 6250 blocks
#define CAP 3072              // staged csr entries per block (12 KB)

union H2F { __half2 h; float f; };

// ========= CSR build: coarse radix (196 buckets) + per-bucket LDS sort =========

// Global coarse histogram (196 bins) via per-block LDS hist.
__global__ __launch_bounds__(256) void k_count(
    const int* __restrict__ dst, int* __restrict__ ctot)
{
    __shared__ int lh[NCB];
    int t = threadIdx.x;
    if (t < NCB) lh[t] = 0;
    __syncthreads();
    int base = blockIdx.x * EPB;
    for (int j = 0; j < EPB; j += 256) {
        int e = base + j + t;
        if (e < EP) {
            int d = (e < Ee) ? dst[e] : (e - Ee);
            atomicAdd(&lh[d >> 10], 1);
        }
    }
    __syncthreads();
    if (t < NCB && lh[t]) atomicAdd(&ctot[t], lh[t]);
}

// Scan coarse totals -> cbase, ccur.
__global__ __launch_bounds__(256) void k_scan(
    const int* __restrict__ ctot, int* __restrict__ cbase,
    int* __restrict__ ccur, int* __restrict__ row_ptr)
{
    __shared__ int s[256];
    int t = threadIdx.x;
    int v = (t < NCB) ? ctot[t] : 0;
    s[t] = v; __syncthreads();
    for (int off = 1; off < 256; off <<= 1) {
        int u = (t >= off) ? s[t - off] : 0;
        __syncthreads();
        s[t] += u;
        __syncthreads();
    }
    if (t < NCB) { cbase[t] = s[t] - v; ccur[t] = s[t] - v; }
    if (t == 0) { cbase[NCB] = EP; row_ptr[Nn] = EP; }
}

// Phase A: LDS multisplit. Reorder the block's 8192 edges into bucket order
// in LDS, then drain with one coalesced burst — every output line is
// assembled within a tight window, so L2 evicts it exactly once (fixes the
// 4x thrash-eviction write amp of direct scattered stores).
// Payload: src (18b) | dst low 10 bits << 18.
__global__ __launch_bounds__(256) void kA_scatter(
    const int* __restrict__ src, const int* __restrict__ dst,
    int* __restrict__ ccur, unsigned* __restrict__ bucketed)
{
    __shared__ unsigned pbuf[EPB];        // 32 KB
    __shared__ int lh[NCB];
    __shared__ int lbase[NCB + 1];
    __shared__ int delta[NCB];
    int t = threadIdx.x;
    if (t < NCB) lh[t] = 0;
    __syncthreads();
    const int base = blockIdx.x * EPB;
    const int nseg = min(EPB, EP - base);
    // pass 1: histogram
    for (int j = t; j < nseg; j += 256) {
        int e = base + j;
        int d = (e < Ee) ? dst[e] : (e - Ee);
        atomicAdd(&lh[d >> 10], 1);
    }
    __syncthreads();
    // scan 196 bins (Hillis-Steele over 256 lanes)
    {
        __shared__ int s[256];
        int v = (t < NCB) ? lh[t] : 0;
        s[t] = v; __syncthreads();
        for (int off = 1; off < 256; off <<= 1) {
            int u = (t >= off) ? s[t - off] : 0;
            __syncthreads();
            s[t] += u;
            __syncthreads();
        }
        if (t < NCB) {
            int ex = s[t] - v;
            lbase[t] = ex;
            lh[t] = ex;                       // reuse as LDS cursor
            int g = v ? atomicAdd(&ccur[t], v) : 0;   // block's global run start
            delta[t] = g - ex;
        }
        if (t == 0) lbase[NCB] = nseg;
    }
    __syncthreads();
    // pass 2: scatter into LDS (bucket-ordered)
    for (int j = t; j < nseg; j += 256) {
        int e = base + j;
        int s, d;
        if (e < Ee) { s = src[e]; d = dst[e]; } else { s = e - Ee; d = s; }
        int pos = atomicAdd(&lh[d >> 10], 1);
        pbuf[pos] = (unsigned)s | ((unsigned)(d & 1023) << 18);
    }
    __syncthreads();
    // pass 3: coalesced burst drain; bucket of j via binary search on lbase
    for (int j = t; j < nseg; j += 256) {
        int lo = 0, hi = NCB - 1;
        while (lo < hi) {
            int mid = (lo + hi + 1) >> 1;
            if (lbase[mid] <= j) lo = mid; else hi = mid - 1;
        }
        bucketed[delta[lo] + j] = pbuf[j];
    }
}

// Phase B: ONE 1024-thread block per coarse bucket; 1024-bin LDS counting
// sort. Region read exactly twice, csr written once. row_ptr analytic.
__global__ __launch_bounds__(1024) void kB_csr(
    const unsigned* __restrict__ bucketed, const int* __restrict__ cbase,
    int* __restrict__ row_ptr, int* __restrict__ csr_src)
{
    __shared__ int bh[1024];
    __shared__ int cur[1024];
    int k = blockIdx.x;
    int beg = cbase[k], end = cbase[k + 1];
    int t = threadIdx.x;
    bh[t] = 0;
    __syncthreads();
    for (int i = beg + t; i < end; i += 1024)
        atomicAdd(&bh[(bucketed[i] >> 18) & 1023], 1);
    __syncthreads();
    int v = bh[t];
    for (int off = 1; off < 1024; off <<= 1) {
        int u = (t >= off) ? bh[t - off] : 0;
        __syncthreads();
        bh[t] += u;
        __syncthreads();
    }
    int pos0 = beg + bh[t] - v;       // exclusive scan
    int node = (k << 10) + t;
    if (node < Nn) row_ptr[node] = pos0;
    cur[t] = pos0;
    __syncthreads();
    for (int i = beg + t; i < end; i += 1024) {
        unsigned p = bucketed[i];
        int pos = atomicAdd(&cur[(p >> 18) & 1023], 1);
        csr_src[pos] = (int)(p & 0x3FFFFu);
    }
}

// ============ per-layer kernels ============

// h line layout per node: 32 B = 8 floats.
//   floats[0..3] = h0..h7 as 4x half2, float[4] low half = h8,
//   float[5] = alpha_s (fp32), float[6] = alpha_d (fp32), float[7] pad.
__global__ __launch_bounds__(256) void k_transform(
    const float* __restrict__ xin, int xstride,
    const float* __restrict__ Wl,
    const float* __restrict__ asrc, const float* __restrict__ adst,
    float* __restrict__ h)
{
    int i = blockIdx.x * blockDim.x + threadIdx.x;
    if (i >= Nn) return;
    const float* xp = xin + (size_t)i * xstride;
    float xi[Hh];
#pragma unroll
    for (int k = 0; k < Hh; ++k) xi[k] = xp[k];
    float hv[Hh];
#pragma unroll
    for (int j = 0; j < Hh; ++j) {
        float s = 0.f;
#pragma unroll
        for (int k = 0; k < Hh; ++k) s += xi[k] * Wl[k * Hh + j];
        hv[j] = s;
    }
    float as = 0.f, ad = 0.f;
#pragma unroll
    for (int j = 0; j < Hh; ++j) { as += hv[j] * asrc[j]; ad += hv[j] * adst[j]; }
    H2F u01, u23, u45, u67, u8p;
    u01.h = __floats2half2_rn(hv[0], hv[1]);
    u23.h = __floats2half2_rn(hv[2], hv[3]);
    u45.h = __floats2half2_rn(hv[4], hv[5]);
    u67.h = __floats2half2_rn(hv[6], hv[7]);
    u8p.h = __floats2half2_rn(hv[8], 0.f);
    float4* hp = (float4*)(h + ((size_t)i << 3));
    hp[0] = make_float4(u01.f, u23.f, u45.f, u67.f);
    hp[1] = make_float4(u8p.f, as, ad, 0.f);
}

// Oct-per-node gather with LDS-staged CSR (8 lanes/node -> 2x wave count
// vs quad to hide gather latency).
// Single-pass softmax: |logits| << 88 so exp never overflows; ratio exact.
__global__ __launch_bounds__(256) void k_node_agg(
    const int* __restrict__ rp, const int* __restrict__ csr,
    const float* __restrict__ h, const float* __restrict__ biasl,
    float* __restrict__ jk, int l)
{
    __shared__ int scsr[CAP];
    __shared__ int srp[NPB + 1];
    const int nbase = blockIdx.x * NPB;
    const int t = threadIdx.x;
    if (t <= NPB) srp[t] = rp[nbase + t];   // nbase+NPB <= Nn; rp[Nn] = EP
    __syncthreads();
    const int beg_blk = srp[0];
    const int nseg = srp[NPB] - beg_blk;
    const bool use_lds = (nseg <= CAP);
    if (use_lds)
        for (int j = t; j < nseg; j += 256) scsr[j] = csr[beg_blk + j];
    __syncthreads();

    const int ni = t >> 3;          // node within block
    const int q  = t & 7;           // lane within oct
    const int i  = nbase + ni;
    const float c = h[((size_t)i << 3) + 6];   // own alpha_d (fp32)
    float a0=0,a1=0,a2=0,a3=0,a4=0,a5=0,a6=0,a7=0,a8=0,den=0;
    if (use_lds) {
        int idx = srp[ni] - beg_blk + q;
        const int iend = srp[ni + 1] - beg_blk;
        int s = (idx < iend) ? scsr[idx] : 0;
        while (idx < iend) {
            int nidx = idx + 8;
            int sn = (nidx < iend) ? scsr[nidx] : 0;   // prefetch next src
            const float4* hp = (const float4*)(h + ((size_t)s << 3));
            float4 F0 = hp[0], F1 = hp[1];
            float lg = F1.y + c;
            lg = lg > 0.f ? lg : 0.2f * lg;            // leaky_relu(0.2)
            float w = __expf(lg);
            H2F u; float2 p;
            u.f = F0.x; p = __half22float2(u.h); a0 += w*p.x; a1 += w*p.y;
            u.f = F0.y; p = __half22float2(u.h); a2 += w*p.x; a3 += w*p.y;
            u.f = F0.z; p = __half22float2(u.h); a4 += w*p.x; a5 += w*p.y;
            u.f = F0.w; p = __half22float2(u.h); a6 += w*p.x; a7 += w*p.y;
            u.f = F1.x; p = __half22float2(u.h); a8 += w*p.x;
            den += w;
            idx = nidx; s = sn;
        }
    } else {
        for (int e = srp[ni] + q; e < srp[ni + 1]; e += 8) {
            int s = csr[e];
            const float4* hp = (const float4*)(h + ((size_t)s << 3));
            float4 F0 = hp[0], F1 = hp[1];
            float lg = F1.y + c;
            lg = lg > 0.f ? lg : 0.2f * lg;
            float w = __expf(lg);
            H2F u; float2 p;
            u.f = F0.x; p = __half22float2(u.h); a0 += w*p.x; a1 += w*p.y;
            u.f = F0.y; p = __half22float2(u.h); a2 += w*p.x; a3 += w*p.y;
            u.f = F0.z; p = __half22float2(u.h); a4 += w*p.x; a5 += w*p.y;
            u.f = F0.w; p = __half22float2(u.h); a6 += w*p.x; a7 += w*p.y;
            u.f = F1.x; p = __half22float2(u.h); a8 += w*p.x;
            den += w;
        }
    }
#pragma unroll
    for (int m = 1; m <= 4; m <<= 1) {
        a0 += __shfl_xor(a0, m); a1 += __shfl_xor(a1, m);
        a2 += __shfl_xor(a2, m); a3 += __shfl_xor(a3, m);
        a4 += __shfl_xor(a4, m); a5 += __shfl_xor(a5, m);
        a6 += __shfl_xor(a6, m); a7 += __shfl_xor(a7, m);
        a8 += __shfl_xor(a8, m); den += __shfl_xor(den, m);
    }
    if (q == 0) {
        float inv = 1.f / den;          // den >= 1 (self-loop term)
        float* jp = jk + (size_t)i * JK + l * Hh;
        float o;
        o = a0*inv + biasl[0]; jp[0] = fmaxf(o, 0.f);
        o = a1*inv + biasl[1]; jp[1] = fmaxf(o, 0.f);
        o = a2*inv + biasl[2]; jp[2] = fmaxf(o, 0.f);
        o = a3*inv + biasl[3]; jp[3] = fmaxf(o, 0.f);
        o = a4*inv + biasl[4]; jp[4] = fmaxf(o, 0.f);
        o = a5*inv + biasl[5]; jp[5] = fmaxf(o, 0.f);
        o = a6*inv + biasl[6]; jp[6] = fmaxf(o, 0.f);
        o = a7*inv + biasl[7]; jp[7] = fmaxf(o, 0.f);
        o = a8*inv + biasl[8]; jp[8] = fmaxf(o, 0.f);
    }
}

// ============ pool + fc ============

// batch is sorted -> graphs are contiguous node ranges. Build range starts.
__global__ __launch_bounds__(256) void k_graph_ptr(
    const int* __restrict__ batch, int* __restrict__ gp)
{
    int i = blockIdx.x * 256 + threadIdx.x;
    if (i >= Nn) return;
    int b = batch[i];
    if (i == 0) {
        for (int g = 0; g <= b; ++g) gp[g] = 0;
    } else {
        int pb = batch[i - 1];
        for (int g = pb + 1; g <= b; ++g) gp[g] = i;
    }
    if (i == Nn - 1) {
        for (int g = b + 1; g <= Gg; ++g) gp[g] = Nn;
    }
}

// Segmented max, one thread per (graph, col). Post-relu values >= 0 and
// init 0 reproduces the isfinite->0 guard for empty graphs.
__global__ __launch_bounds__(256) void k_pool_seg(
    const float* __restrict__ jk, const int* __restrict__ gp,
    float* __restrict__ pooled)
{
    int t = blockIdx.x * 256 + threadIdx.x;
    if (t >= Gg * JK) return;
    int g = t / JK, col = t - g * JK;
    int beg = gp[g], end = gp[g + 1];
    float m = 0.f;
    for (int i = beg; i < end; ++i)
        m = fmaxf(m, jk[(size_t)i * JK + col]);
    pooled[t] = m;
}

__global__ __launch_bounds__(256) void k_fc(
    const float* __restrict__ pooled, const float* __restrict__ fcw,
    const float* __restrict__ fcb, float* __restrict__ out)
{
    int t = blockIdx.x * blockDim.x + threadIdx.x;
    if (t >= Gg * Cc) return;
    int g = t / Cc, c = t - g * Cc;
    float s = fcb[c];
    const float* pp = pooled + (size_t)g * JK;
#pragma unroll
    for (int j = 0; j < JK; ++j) s += pp[j] * fcw[j * Cc + c];
    out[t] = s;
}

extern "C" void kernel_launch(void* const* d_in, const int* in_sizes, int n_in,
                              void* d_out, int out_size, void* d_ws, size_t ws_size,
                              hipStream_t stream) {
    const float* x      = (const float*)d_in[0];   // [N,9]
    const int*   ei     = (const int*)d_in[1];     // [2,E]: src row then dst row
    const int*   batch  = (const int*)d_in[2];     // [N] sorted
    const float* W      = (const float*)d_in[3];   // [L,9,9]
    const float* a_src  = (const float*)d_in[4];   // [L,9]
    const float* a_dst  = (const float*)d_in[5];   // [L,9]
    const float* bias   = (const float*)d_in[6];   // [L,9]
    const float* fc_w   = (const float*)d_in[7];   // [36,2]
    const float* fc_b   = (const float*)d_in[8];   // [2]
    float* out = (float*)d_out;

    // Workspace layout (~63 MB live). bucketed aliases jk (dead before jk
    // is first written — same-stream ordering).
    float* ws        = (float*)d_ws;
    float* h         = ws;                                // Nn*8 floats (6.4MB)
    float* jk        = h + (size_t)Nn * 8;                // Nn*JK (28.8MB)
    float* pooled    = jk + (size_t)Nn * JK;              // Gg*JK
    int* row_ptr     = (int*)(pooled + (size_t)Gg * JK);  // Nn+1
    int* gp          = row_ptr + Nn + 1;                  // Gg+1
    int* ctot        = gp + Gg + 1;                       // NCB
    int* cbase       = ctot + NCB;                        // NCB+1
    int* ccur        = cbase + NCB + 1;                   // NCB
    int* csr_src     = ccur + NCB;                        // EP (26.4MB)
    unsigned* bucketed = (unsigned*)jk;                   // EP alias (26.4MB)

    const int* srcp = ei;
    const int* dstp = ei + Ee;

    // CSR build (edge structure is layer-invariant)
    hipMemsetAsync(ctot, 0, NCB * sizeof(int), stream);
    k_count   <<<NBLKA, 256, 0, stream>>>(dstp, ctot);
    k_scan    <<<1, 256, 0, stream>>>(ctot, cbase, ccur, row_ptr);
    kA_scatter<<<NBLKA, 256, 0, stream>>>(srcp, dstp, ccur, bucketed);
    kB_csr    <<<NCB, 1024, 0, stream>>>(bucketed, cbase, row_ptr, csr_src);

    for (int l = 0; l < Ll; ++l) {
        const float* xin = (l == 0) ? x : (jk + (size_t)(l - 1) * Hh);
        int xstride      = (l == 0) ? Hh : JK;
        k_transform<<<NB, 256, 0, stream>>>(xin, xstride, W + l * Hh * Hh,
                                            a_src + l * Hh, a_dst + l * Hh, h);
        k_node_agg<<<NAB, 256, 0, stream>>>(row_ptr, csr_src,
                                            h, bias + l * Hh, jk, l);
    }
    k_graph_ptr<<<NB, 256, 0, stream>>>(batch, gp);
    k_pool_seg<<<(Gg * JK + 255) / 256, 256, 0, stream>>>(jk, gp, pooled);
    k_fc<<<(Gg * Cc + 255) / 256, 256, 0, stream>>>(pooled, fc_w, fc_b, out);
}

// Round 9
// 540.572 us; speedup vs baseline: 1.5642x; 1.0250x over previous
//
#include <hip/hip_runtime.h>
#include <hip/hip_fp16.h>

// Problem constants (from reference)
#define Nn 200000
#define Ee 6400000
#define EP 6600000            // Ee + Nn self loops
#define Hh 9
#define Ll 4
#define Gg 2000
#define Cc 2
#define JK 36                 // Ll * Hh
#define NCB ((Nn + 1023) >> 10) // 196 coarse buckets (1024 nodes each)
#define EPB 8192              // edges per phase-A block
#define NBLKA ((EP + EPB - 1) / EPB) // 806
#define NB ((Nn + 255) / 256) // 782
#define NPB 32                // nodes per k_node_agg block (oct per node)
#define NAB (Nn / NPB)        // 6250 blocks
#define CAP 3072              // staged csr entries per block (12 KB)
#define HTS (NCB + 1)         // histT row stride

union H2F { __half2 h; float f; };

// ========= CSR build: block-major multisplit + per-bucket LDS sort =========

// Phase A: per-block LDS multisplit, drained BLOCK-MAJOR (straight coalesced
// copy, no global coordination). Per-block bucket offsets -> histT row;
// global bucket totals -> ctot (196 atomics/block).
// Payload: src (18b) | dst low 10 bits << 18.
__global__ __launch_bounds__(256) void kA_scatter(
    const int* __restrict__ src, const int* __restrict__ dst,
    int* __restrict__ ctot, int* __restrict__ histT,
    unsigned* __restrict__ bucketed)
{
    __shared__ unsigned pbuf[EPB];        // 32 KB
    __shared__ int lh[NCB];
    __shared__ int s[256];
    int t = threadIdx.x;
    if (t < NCB) lh[t] = 0;
    __syncthreads();
    const int base = blockIdx.x * EPB;
    const int nseg = min(EPB, EP - base);
    // pass 1: histogram (dst only)
    for (int j = t; j < nseg; j += 256) {
        int e = base + j;
        int d = (e < Ee) ? dst[e] : (e - Ee);
        atomicAdd(&lh[d >> 10], 1);
    }
    __syncthreads();
    // exclusive scan of 196 bins
    int v = (t < NCB) ? lh[t] : 0;
    s[t] = v; __syncthreads();
    for (int off = 1; off < 256; off <<= 1) {
        int u = (t >= off) ? s[t - off] : 0;
        __syncthreads();
        s[t] += u;
        __syncthreads();
    }
    int* hrow = histT + (size_t)blockIdx.x * HTS;
    if (t < NCB) {
        int ex = s[t] - v;
        lh[t] = ex;                        // LDS cursor
        hrow[t] = ex;                      // run starts for kB
        if (v) atomicAdd(&ctot[t], v);
    }
    if (t == 0) hrow[NCB] = nseg;
    __syncthreads();
    // pass 2: scatter into LDS (bucket-ordered within block)
    for (int j = t; j < nseg; j += 256) {
        int e = base + j;
        int sv, d;
        if (e < Ee) { sv = src[e]; d = dst[e]; } else { sv = e - Ee; d = sv; }
        int pos = atomicAdd(&lh[d >> 10], 1);
        pbuf[pos] = (unsigned)sv | ((unsigned)(d & 1023) << 18);
    }
    __syncthreads();
    // pass 3: straight coalesced drain, block-major
    for (int j = t; j < nseg; j += 256)
        bucketed[base + j] = pbuf[j];
}

// Scan coarse totals -> cbase.
__global__ __launch_bounds__(256) void k_scan(
    const int* __restrict__ ctot, int* __restrict__ cbase,
    int* __restrict__ row_ptr)
{
    __shared__ int s[256];
    int t = threadIdx.x;
    int v = (t < NCB) ? ctot[t] : 0;
    s[t] = v; __syncthreads();
    for (int off = 1; off < 256; off <<= 1) {
        int u = (t >= off) ? s[t - off] : 0;
        __syncthreads();
        s[t] += u;
        __syncthreads();
    }
    if (t < NCB) cbase[t] = s[t] - v;
    if (t == 0) { cbase[NCB] = EP; row_ptr[Nn] = EP; }
}

// Phase B: ONE 1024-thread block per coarse bucket. Its entries live in 806
// short runs (block-major regions, bounds from histT). Two passes:
// 1024-bin hist -> scan -> scatter into private csr window. row_ptr analytic.
__global__ __launch_bounds__(1024) void kB_csr(
    const unsigned* __restrict__ bucketed, const int* __restrict__ histT,
    const int* __restrict__ cbase, int* __restrict__ row_ptr,
    int* __restrict__ csr_src)
{
    __shared__ int bh[1024];
    __shared__ int cur[1024];
    const int k = blockIdx.x;
    const int t = threadIdx.x;
    const int w = t >> 6, lane = t & 63;  // 16 waves
    bh[t] = 0;
    __syncthreads();
    for (int b = w; b < NBLKA; b += 16) {
        const int* hrow = histT + (size_t)b * HTS;
        int s0 = hrow[k], s1 = hrow[k + 1];   // same addr all lanes: broadcast
        int rb = b * EPB;
        for (int j = s0 + lane; j < s1; j += 64)
            atomicAdd(&bh[(bucketed[rb + j] >> 18) & 1023], 1);
    }
    __syncthreads();
    int v = bh[t];
    for (int off = 1; off < 1024; off <<= 1) {
        int u = (t >= off) ? bh[t - off] : 0;
        __syncthreads();
        bh[t] += u;
        __syncthreads();
    }
    int pos0 = cbase[k] + bh[t] - v;      // exclusive scan
    int node = (k << 10) + t;
    if (node < Nn) row_ptr[node] = pos0;
    cur[t] = pos0;
    __syncthreads();
    for (int b = w; b < NBLKA; b += 16) {
        const int* hrow = histT + (size_t)b * HTS;
        int s0 = hrow[k], s1 = hrow[k + 1];
        int rb = b * EPB;
        for (int j = s0 + lane; j < s1; j += 64) {
            unsigned p = bucketed[rb + j];
            int pos = atomicAdd(&cur[(p >> 18) & 1023], 1);
            csr_src[pos] = (int)(p & 0x3FFFFu);
        }
    }
}

// ============ per-layer kernels ============

// h line layout per node: 32 B = 8 floats.
//   floats[0..3] = h0..h7 as 4x half2, float[4] low half = h8,
//   float[5] = alpha_s (fp32), float[6] = alpha_d (fp32), float[7] pad.
__global__ __launch_bounds__(256) void k_transform(
    const float* __restrict__ xin, int xstride,
    const float* __restrict__ Wl,
    const float* __restrict__ asrc, const float* __restrict__ adst,
    float* __restrict__ h)
{
    int i = blockIdx.x * blockDim.x + threadIdx.x;
    if (i >= Nn) return;
    const float* xp = xin + (size_t)i * xstride;
    float xi[Hh];
#pragma unroll
    for (int k = 0; k < Hh; ++k) xi[k] = xp[k];
    float hv[Hh];
#pragma unroll
    for (int j = 0; j < Hh; ++j) {
        float s = 0.f;
#pragma unroll
        for (int k = 0; k < Hh; ++k) s += xi[k] * Wl[k * Hh + j];
        hv[j] = s;
    }
    float as = 0.f, ad = 0.f;
#pragma unroll
    for (int j = 0; j < Hh; ++j) { as += hv[j] * asrc[j]; ad += hv[j] * adst[j]; }
    H2F u01, u23, u45, u67, u8p;
    u01.h = __floats2half2_rn(hv[0], hv[1]);
    u23.h = __floats2half2_rn(hv[2], hv[3]);
    u45.h = __floats2half2_rn(hv[4], hv[5]);
    u67.h = __floats2half2_rn(hv[6], hv[7]);
    u8p.h = __floats2half2_rn(hv[8], 0.f);
    float4* hp = (float4*)(h + ((size_t)i << 3));
    hp[0] = make_float4(u01.f, u23.f, u45.f, u67.f);
    hp[1] = make_float4(u8p.f, as, ad, 0.f);
}

// Oct-per-node gather with LDS-staged CSR.
// Single-pass softmax: |logits| << 88 so exp never overflows; ratio exact.
__global__ __launch_bounds__(256) void k_node_agg(
    const int* __restrict__ rp, const int* __restrict__ csr,
    const float* __restrict__ h, const float* __restrict__ biasl,
    float* __restrict__ jk, int l)
{
    __shared__ int scsr[CAP];
    __shared__ int srp[NPB + 1];
    const int nbase = blockIdx.x * NPB;
    const int t = threadIdx.x;
    if (t <= NPB) srp[t] = rp[nbase + t];   // nbase+NPB <= Nn; rp[Nn] = EP
    __syncthreads();
    const int beg_blk = srp[0];
    const int nseg = srp[NPB] - beg_blk;
    const bool use_lds = (nseg <= CAP);
    if (use_lds)
        for (int j = t; j < nseg; j += 256) scsr[j] = csr[beg_blk + j];
    __syncthreads();

    const int ni = t >> 3;          // node within block
    const int q  = t & 7;           // lane within oct
    const int i  = nbase + ni;
    const float c = h[((size_t)i << 3) + 6];   // own alpha_d (fp32)
    float a0=0,a1=0,a2=0,a3=0,a4=0,a5=0,a6=0,a7=0,a8=0,den=0;
    if (use_lds) {
        int idx = srp[ni] - beg_blk + q;
        const int iend = srp[ni + 1] - beg_blk;
        int s = (idx < iend) ? scsr[idx] : 0;
        while (idx < iend) {
            int nidx = idx + 8;
            int sn = (nidx < iend) ? scsr[nidx] : 0;   // prefetch next src
            const float4* hp = (const float4*)(h + ((size_t)s << 3));
            float4 F0 = hp[0], F1 = hp[1];
            float lg = F1.y + c;
            lg = lg > 0.f ? lg : 0.2f * lg;            // leaky_relu(0.2)
            float w = __expf(lg);
            H2F u; float2 p;
            u.f = F0.x; p = __half22float2(u.h); a0 += w*p.x; a1 += w*p.y;
            u.f = F0.y; p = __half22float2(u.h); a2 += w*p.x; a3 += w*p.y;
            u.f = F0.z; p = __half22float2(u.h); a4 += w*p.x; a5 += w*p.y;
            u.f = F0.w; p = __half22float2(u.h); a6 += w*p.x; a7 += w*p.y;
            u.f = F1.x; p = __half22float2(u.h); a8 += w*p.x;
            den += w;
            idx = nidx; s = sn;
        }
    } else {
        for (int e = srp[ni] + q; e < srp[ni + 1]; e += 8) {
            int s = csr[e];
            const float4* hp = (const float4*)(h + ((size_t)s << 3));
            float4 F0 = hp[0], F1 = hp[1];
            float lg = F1.y + c;
            lg = lg > 0.f ? lg : 0.2f * lg;
            float w = __expf(lg);
            H2F u; float2 p;
            u.f = F0.x; p = __half22float2(u.h); a0 += w*p.x; a1 += w*p.y;
            u.f = F0.y; p = __half22float2(u.h); a2 += w*p.x; a3 += w*p.y;
            u.f = F0.z; p = __half22float2(u.h); a4 += w*p.x; a5 += w*p.y;
            u.f = F0.w; p = __half22float2(u.h); a6 += w*p.x; a7 += w*p.y;
            u.f = F1.x; p = __half22float2(u.h); a8 += w*p.x;
            den += w;
        }
    }
#pragma unroll
    for (int m = 1; m <= 4; m <<= 1) {
        a0 += __shfl_xor(a0, m); a1 += __shfl_xor(a1, m);
        a2 += __shfl_xor(a2, m); a3 += __shfl_xor(a3, m);
        a4 += __shfl_xor(a4, m); a5 += __shfl_xor(a5, m);
        a6 += __shfl_xor(a6, m); a7 += __shfl_xor(a7, m);
        a8 += __shfl_xor(a8, m); den += __shfl_xor(den, m);
    }
    if (q == 0) {
        float inv = 1.f / den;          // den >= 1 (self-loop term)
        float* jp = jk + (size_t)i * JK + l * Hh;
        float o;
        o = a0*inv + biasl[0]; jp[0] = fmaxf(o, 0.f);
        o = a1*inv + biasl[1]; jp[1] = fmaxf(o, 0.f);
        o = a2*inv + biasl[2]; jp[2] = fmaxf(o, 0.f);
        o = a3*inv + biasl[3]; jp[3] = fmaxf(o, 0.f);
        o = a4*inv + biasl[4]; jp[4] = fmaxf(o, 0.f);
        o = a5*inv + biasl[5]; jp[5] = fmaxf(o, 0.f);
        o = a6*inv + biasl[6]; jp[6] = fmaxf(o, 0.f);
        o = a7*inv + biasl[7]; jp[7] = fmaxf(o, 0.f);
        o = a8*inv + biasl[8]; jp[8] = fmaxf(o, 0.f);
    }
}

// ============ pool + fc ============

// batch is sorted -> graphs are contiguous node ranges. Build range starts.
__global__ __launch_bounds__(256) void k_graph_ptr(
    const int* __restrict__ batch, int* __restrict__ gp)
{
    int i = blockIdx.x * 256 + threadIdx.x;
    if (i >= Nn) return;
    int b = batch[i];
    if (i == 0) {
        for (int g = 0; g <= b; ++g) gp[g] = 0;
    } else {
        int pb = batch[i - 1];
        for (int g = pb + 1; g <= b; ++g) gp[g] = i;
    }
    if (i == Nn - 1) {
        for (int g = b + 1; g <= Gg; ++g) gp[g] = Nn;
    }
}

// Segmented max, one thread per (graph, col). Post-relu values >= 0 and
// init 0 reproduces the isfinite->0 guard for empty graphs.
__global__ __launch_bounds__(256) void k_pool_seg(
    const float* __restrict__ jk, const int* __restrict__ gp,
    float* __restrict__ pooled)
{
    int t = blockIdx.x * 256 + threadIdx.x;
    if (t >= Gg * JK) return;
    int g = t / JK, col = t - g * JK;
    int beg = gp[g], end = gp[g + 1];
    float m = 0.f;
    for (int i = beg; i < end; ++i)
        m = fmaxf(m, jk[(size_t)i * JK + col]);
    pooled[t] = m;
}

__global__ __launch_bounds__(256) void k_fc(
    const float* __restrict__ pooled, const float* __restrict__ fcw,
    const float* __restrict__ fcb, float* __restrict__ out)
{
    int t = blockIdx.x * blockDim.x + threadIdx.x;
    if (t >= Gg * Cc) return;
    int g = t / Cc, c = t - g * Cc;
    float s = fcb[c];
    const float* pp = pooled + (size_t)g * JK;
#pragma unroll
    for (int j = 0; j < JK; ++j) s += pp[j] * fcw[j * Cc + c];
    out[t] = s;
}

extern "C" void kernel_launch(void* const* d_in, const int* in_sizes, int n_in,
                              void* d_out, int out_size, void* d_ws, size_t ws_size,
                              hipStream_t stream) {
    const float* x      = (const float*)d_in[0];   // [N,9]
    const int*   ei     = (const int*)d_in[1];     // [2,E]: src row then dst row
    const int*   batch  = (const int*)d_in[2];     // [N] sorted
    const float* W      = (const float*)d_in[3];   // [L,9,9]
    const float* a_src  = (const float*)d_in[4];   // [L,9]
    const float* a_dst  = (const float*)d_in[5];   // [L,9]
    const float* bias   = (const float*)d_in[6];   // [L,9]
    const float* fc_w   = (const float*)d_in[7];   // [36,2]
    const float* fc_b   = (const float*)d_in[8];   // [2]
    float* out = (float*)d_out;

    // Workspace layout (~63 MB live). histT aliases h, bucketed aliases jk —
    // both dead before h/jk are first written (same-stream ordering).
    float* ws        = (float*)d_ws;
    float* h         = ws;                                // Nn*8 floats (6.4MB)
    float* jk        = h + (size_t)Nn * 8;                // Nn*JK (28.8MB)
    float* pooled    = jk + (size_t)Nn * JK;              // Gg*JK
    int* row_ptr     = (int*)(pooled + (size_t)Gg * JK);  // Nn+1
    int* gp          = row_ptr + Nn + 1;                  // Gg+1
    int* ctot        = gp + Gg + 1;                       // NCB
    int* cbase       = ctot + NCB;                        // NCB+1
    int* csr_src     = cbase + NCB + 1;                   // EP (26.4MB)
    int* histT       = (int*)h;                           // NBLKA*HTS (0.64MB)
    unsigned* bucketed = (unsigned*)jk;                   // EP alias (26.4MB)

    const int* srcp = ei;
    const int* dstp = ei + Ee;

    // CSR build (edge structure is layer-invariant)
    hipMemsetAsync(ctot, 0, NCB * sizeof(int), stream);
    kA_scatter<<<NBLKA, 256, 0, stream>>>(srcp, dstp, ctot, histT, bucketed);
    k_scan    <<<1, 256, 0, stream>>>(ctot, cbase, row_ptr);
    kB_csr    <<<NCB, 1024, 0, stream>>>(bucketed, histT, cbase, row_ptr, csr_src);

    for (int l = 0; l < Ll; ++l) {
        const float* xin = (l == 0) ? x : (jk + (size_t)(l - 1) * Hh);
        int xstride      = (l == 0) ? Hh : JK;
        k_transform<<<NB, 256, 0, stream>>>(xin, xstride, W + l * Hh * Hh,
                                            a_src + l * Hh, a_dst + l * Hh, h);
        k_node_agg<<<NAB, 256, 0, stream>>>(row_ptr, csr_src,
                                            h, bias + l * Hh, jk, l);
    }
    k_graph_ptr<<<NB, 256, 0, stream>>>(batch, gp);
    k_pool_seg<<<(Gg * JK + 255) / 256, 256, 0, stream>>>(jk, gp, pooled);
    k_fc<<<(Gg * Cc + 255) / 256, 256, 0, stream>>>(pooled, fc_w, fc_b, out);
}